// Round 11
// baseline (171.548 us; speedup 1.0000x reference)
//
#include <hip/hip_runtime.h>
#include <stdint.h>
#include <math.h>

// ---------------------------------------------------------------------------
// Threefry-2x32 (JAX-compatible, 20 rounds)
// ---------------------------------------------------------------------------
#define TF_ROUND(r) do { x0 += x1; x1 = (x1 << (r)) | (x1 >> (32 - (r))); x1 ^= x0; } while (0)

__device__ __forceinline__ void threefry2x32(uint32_t k0, uint32_t k1,
                                             uint32_t x0, uint32_t x1,
                                             uint32_t& y0, uint32_t& y1)
{
    uint32_t k2 = k0 ^ k1 ^ 0x1BD11BDAu;
    x0 += k0; x1 += k1;
    TF_ROUND(13); TF_ROUND(15); TF_ROUND(26); TF_ROUND(6);
    x0 += k1; x1 += k2 + 1u;
    TF_ROUND(17); TF_ROUND(29); TF_ROUND(16); TF_ROUND(24);
    x0 += k2; x1 += k0 + 2u;
    TF_ROUND(13); TF_ROUND(15); TF_ROUND(26); TF_ROUND(6);
    x0 += k0; x1 += k1 + 3u;
    TF_ROUND(17); TF_ROUND(29); TF_ROUND(16); TF_ROUND(24);
    x0 += k1; x1 += k2 + 4u;
    TF_ROUND(13); TF_ROUND(15); TF_ROUND(26); TF_ROUND(6);
    y0 = x0 + k2; y1 = x1 + k0 + 5u;
}

__device__ __forceinline__ void wave_red2(double& s, double& q) {
    for (int off = 32; off > 0; off >>= 1) {
        s += __shfl_down(s, off);
        q += __shfl_down(q, off);
    }
}

__device__ __forceinline__ float sigf(float x) { return 0.5f + 0.5f * tanhf(0.5f * x); }

// ---------------------------------------------------------------------------
// dw0: depthwise 3x3 s2 p1, 56->28 (~47us measured; unchanged).
// psum: sum [c*256+n], sumsq [16384 + c*256+n].
// ---------------------------------------------------------------------------
__global__ __launch_bounds__(256) void dw0_kernel(
    const float* __restrict__ in, const float* __restrict__ wts,
    float* __restrict__ out, double* __restrict__ psum)
{
    __shared__ float tile[3136];
    __shared__ double sred[8];
    const int tid = threadIdx.x, lane = tid & 63, wid = tid >> 6;
    const int blk = blockIdx.x;
    const int n = blk >> 6, c = blk & 63;

    const float4* ip4 = (const float4*)(in + (size_t)blk * 3136);
    float4* tp4 = (float4*)tile;
#pragma unroll
    for (int r = 0; r < 3; ++r) tp4[tid + r * 256] = ip4[tid + r * 256];
    if (tid < 16) tp4[768 + tid] = ip4[768 + tid];
    float w9[9];
#pragma unroll
    for (int k = 0; k < 9; ++k) w9[k] = wts[c * 9 + k];
    __syncthreads();

    double ls = 0.0, lq = 0.0;
    if (tid < 196) {
        const int oh = tid / 7, ow0 = (tid - oh * 7) * 4;
        const int col0 = 2 * ow0 - 1;
        float rv[3][9];
#pragma unroll
        for (int kh = 0; kh < 3; ++kh) {
            const int ih = 2 * oh - 1 + kh;           // max 55 < 56
            if (ih >= 0) {
                const float* rp = tile + ih * 56 + col0;
                rv[kh][0] = (col0 >= 0) ? rp[0] : 0.f;
#pragma unroll
                for (int j = 1; j < 9; ++j) rv[kh][j] = rp[j];
            } else {
#pragma unroll
                for (int j = 0; j < 9; ++j) rv[kh][j] = 0.f;
            }
        }
        float a0 = 0.f, a1 = 0.f, a2 = 0.f, a3 = 0.f;
#pragma unroll
        for (int kh = 0; kh < 3; ++kh)
#pragma unroll
            for (int kw = 0; kw < 3; ++kw) {
                const float w = w9[kh * 3 + kw];
                a0 = fmaf(rv[kh][0 + kw], w, a0);
                a1 = fmaf(rv[kh][2 + kw], w, a1);
                a2 = fmaf(rv[kh][4 + kw], w, a2);
                a3 = fmaf(rv[kh][6 + kw], w, a3);
            }
        *(float4*)(out + (size_t)blk * 784 + oh * 28 + ow0) = make_float4(a0, a1, a2, a3);
        ls = (double)a0 + (double)a1 + (double)a2 + (double)a3;
        lq = (double)a0 * a0 + (double)a1 * a1 + (double)a2 * a2 + (double)a3 * a3;
    }
    wave_red2(ls, lq);
    if (lane == 0) { sred[wid] = ls; sred[4 + wid] = lq; }
    __syncthreads();
    if (tid == 0) {
        psum[c * 256 + n] = sred[0] + sred[1] + sred[2] + sred[3];
        psum[16384 + c * 256 + n] = sred[4] + sred[5] + sred[6] + sred[7];
    }
}

// ---------------------------------------------------------------------------
// pw0_f: FUSED st0 finalize (64ch x 256 partials, 16 ch/wave, coalesced) +
// 1x1 conv 64->10 with BN+ReLU, float4 pixels. 196 blocks x 256 thr.
// psum out [oc*196+blk] (+1960).
// ---------------------------------------------------------------------------
__global__ __launch_bounds__(256) void pw0_f(
    const float* __restrict__ in, const float* __restrict__ wts,
    const double* __restrict__ psumA,
    const float* __restrict__ g, const float* __restrict__ b,
    float* __restrict__ out, double* __restrict__ psum)
{
    __shared__ float sw[640], sA[64], sB[64];
    __shared__ double srs[10][4], srq[10][4];
    const int tid = threadIdx.x, lane = tid & 63, wid = tid >> 6;
    for (int i = tid; i < 640; i += 256) sw[i] = wts[i];
    for (int c = wid * 16; c < wid * 16 + 16; ++c) {     // st0 finalize
        double s = 0.0, q = 0.0;
#pragma unroll
        for (int i = lane; i < 256; i += 64) {
            s += psumA[c * 256 + i];
            q += psumA[16384 + c * 256 + i];
        }
        wave_red2(s, q);
        if (lane == 0) {
            double mean = s / 200704.0;
            double var = q / 200704.0 - mean * mean;
            double A = (1.0 / sqrt(var + 1e-5)) * (double)g[c];
            sA[c] = (float)A;
            sB[c] = (float)((double)b[c] - mean * A);
        }
    }
    __syncthreads();

    const int p = blockIdx.x * 256 + tid;       // [0, 50176) quads
    const int n = p / 196, sp4 = p - n * 196;
    const float4* ip4 = (const float4*)in + (size_t)n * 12544 + sp4;
    float4 acc[10];
#pragma unroll
    for (int oc = 0; oc < 10; ++oc) acc[oc] = make_float4(0.f, 0.f, 0.f, 0.f);
#pragma unroll 8
    for (int c = 0; c < 64; ++c) {
        float4 v = ip4[c * 196];
        const float A = sA[c], B = sB[c];
        v.x = fmaxf(fmaf(v.x, A, B), 0.f);
        v.y = fmaxf(fmaf(v.y, A, B), 0.f);
        v.z = fmaxf(fmaf(v.z, A, B), 0.f);
        v.w = fmaxf(fmaf(v.w, A, B), 0.f);
#pragma unroll
        for (int oc = 0; oc < 10; ++oc) {
            const float wv = sw[oc * 64 + c];
            acc[oc].x = fmaf(v.x, wv, acc[oc].x);
            acc[oc].y = fmaf(v.y, wv, acc[oc].y);
            acc[oc].z = fmaf(v.z, wv, acc[oc].z);
            acc[oc].w = fmaf(v.w, wv, acc[oc].w);
        }
    }
#pragma unroll
    for (int oc = 0; oc < 10; ++oc)
        ((float4*)out)[(size_t)(n * 10 + oc) * 196 + sp4] = acc[oc];

#pragma unroll
    for (int oc = 0; oc < 10; ++oc) {
        double s = (double)acc[oc].x + (double)acc[oc].y + (double)acc[oc].z + (double)acc[oc].w;
        double q = (double)acc[oc].x * acc[oc].x + (double)acc[oc].y * acc[oc].y
                 + (double)acc[oc].z * acc[oc].z + (double)acc[oc].w * acc[oc].w;
        wave_red2(s, q);
        if (lane == 0) { srs[oc][wid] = s; srq[oc][wid] = q; }
    }
    __syncthreads();
    if (tid < 10) {
        psum[tid * 196 + blockIdx.x] = srs[tid][0] + srs[tid][1] + srs[tid][2] + srs[tid][3];
        psum[1960 + tid * 196 + blockIdx.x] = srq[tid][0] + srq[tid][1] + srq[tid][2] + srq[tid][3];
    }
}

// ---------------------------------------------------------------------------
// dw_mid_f: 28->14 depthwise with FUSED st1 finalize (channel c, wave0).
// 2560 blocks = (n*10+c), 256 thr. psumIn [oc*196+i] (+1960).
// psumOut [c*256+n] (+2560). (unchanged from R10)
// ---------------------------------------------------------------------------
__global__ __launch_bounds__(256) void dw_mid_f(
    const float* __restrict__ in, const float* __restrict__ wts,
    const double* __restrict__ psumIn,
    const float* __restrict__ g, const float* __restrict__ b,
    float* __restrict__ out, double* __restrict__ psum)
{
    __shared__ float tile[784];
    __shared__ double sred[8];
    __shared__ float sAB[2];
    const int tid = threadIdx.x, lane = tid & 63, wid = tid >> 6;
    const int blk = blockIdx.x;
    const int n = blk / 10, c = blk - n * 10;

    if (wid == 0) {
        double s = 0.0, q = 0.0;
        for (int i = lane; i < 196; i += 64) {
            s += psumIn[c * 196 + i];
            q += psumIn[1960 + c * 196 + i];
        }
        wave_red2(s, q);
        if (lane == 0) {
            double mean = s / 200704.0;
            double var = q / 200704.0 - mean * mean;
            double A = (1.0 / sqrt(var + 1e-5)) * (double)g[c];
            sAB[0] = (float)A;
            sAB[1] = (float)((double)b[c] - mean * A);
        }
    }
    float w9[9];
#pragma unroll
    for (int k = 0; k < 9; ++k) w9[k] = wts[c * 9 + k];
    __syncthreads();

    const float A = sAB[0], B = sAB[1];
    const float4* ip4 = (const float4*)(in + (size_t)blk * 784);
    if (tid < 196) {
        float4 v = ip4[tid];
        v.x = fmaxf(fmaf(v.x, A, B), 0.f);
        v.y = fmaxf(fmaf(v.y, A, B), 0.f);
        v.z = fmaxf(fmaf(v.z, A, B), 0.f);
        v.w = fmaxf(fmaf(v.w, A, B), 0.f);
        ((float4*)tile)[tid] = v;
    }
    __syncthreads();

    double ls = 0.0, lq = 0.0;
    if (tid < 196) {
        const int oh = tid / 14, ow = tid - oh * 14;
        float acc = 0.f;
#pragma unroll
        for (int kh = 0; kh < 3; ++kh) {
            const int ih = 2 * oh - 1 + kh;           // max 27 < 28
            if (ih < 0) continue;
#pragma unroll
            for (int kw = 0; kw < 3; ++kw) {
                const int iw = 2 * ow - 1 + kw;
                if (iw < 0) continue;
                acc = fmaf(tile[ih * 28 + iw], w9[kh * 3 + kw], acc);
            }
        }
        out[(size_t)blk * 196 + tid] = acc;
        ls = (double)acc; lq = (double)acc * (double)acc;
    }
    wave_red2(ls, lq);
    if (lane == 0) { sred[wid] = ls; sred[4 + wid] = lq; }
    __syncthreads();
    if (tid == 0) {
        psum[c * 256 + n] = sred[0] + sred[1] + sred[2] + sred[3];
        psum[2560 + c * 256 + n] = sred[4] + sred[5] + sred[6] + sred[7];
    }
}

// ---------------------------------------------------------------------------
// pw_mid4_f: 1x1 10->10 over 196px planes (float4 quads), FUSED 10-ch stats
// (psumIn [c*256+i] (+2560)). 49 blocks x 256 thr. psumOut [oc*49+b] (+490).
// (unchanged from R10)
// ---------------------------------------------------------------------------
__global__ __launch_bounds__(256) void pw_mid4_f(
    const float* __restrict__ in, const float* __restrict__ wts,
    const double* __restrict__ psumIn, double cnt,
    const float* __restrict__ g, const float* __restrict__ b,
    float* __restrict__ out, double* __restrict__ psum)
{
    __shared__ float sw[100], sA[10], sB[10];
    __shared__ double srs[10][4], srq[10][4];
    const int tid = threadIdx.x, lane = tid & 63, wid = tid >> 6;
    if (tid < 100) sw[tid] = wts[tid];
    for (int c = wid; c < 10; c += 4) {
        double s = 0.0, q = 0.0;
        for (int i = lane; i < 256; i += 64) {
            s += psumIn[c * 256 + i];
            q += psumIn[2560 + c * 256 + i];
        }
        wave_red2(s, q);
        if (lane == 0) {
            double mean = s / cnt;
            double var = q / cnt - mean * mean;
            double A = (1.0 / sqrt(var + 1e-5)) * (double)g[c];
            sA[c] = (float)A;
            sB[c] = (float)((double)b[c] - mean * A);
        }
    }
    __syncthreads();

    const int p = blockIdx.x * 256 + tid;       // [0, 12544) quads
    const int n = p / 49, q4 = p - n * 49;
    const float4* ip4 = (const float4*)in + (size_t)n * 490 + q4;
    float4 acc[10];
#pragma unroll
    for (int oc = 0; oc < 10; ++oc) acc[oc] = make_float4(0.f, 0.f, 0.f, 0.f);
#pragma unroll
    for (int c = 0; c < 10; ++c) {
        float4 v = ip4[c * 49];
        const float A = sA[c], B = sB[c];
        v.x = fmaxf(fmaf(v.x, A, B), 0.f);
        v.y = fmaxf(fmaf(v.y, A, B), 0.f);
        v.z = fmaxf(fmaf(v.z, A, B), 0.f);
        v.w = fmaxf(fmaf(v.w, A, B), 0.f);
#pragma unroll
        for (int oc = 0; oc < 10; ++oc) {
            const float wv = sw[oc * 10 + c];
            acc[oc].x = fmaf(v.x, wv, acc[oc].x);
            acc[oc].y = fmaf(v.y, wv, acc[oc].y);
            acc[oc].z = fmaf(v.z, wv, acc[oc].z);
            acc[oc].w = fmaf(v.w, wv, acc[oc].w);
        }
    }
#pragma unroll
    for (int oc = 0; oc < 10; ++oc)
        ((float4*)out)[(size_t)n * 490 + oc * 49 + q4] = acc[oc];

#pragma unroll
    for (int oc = 0; oc < 10; ++oc) {
        double s = (double)acc[oc].x + (double)acc[oc].y + (double)acc[oc].z + (double)acc[oc].w;
        double qq = (double)acc[oc].x * acc[oc].x + (double)acc[oc].y * acc[oc].y
                  + (double)acc[oc].z * acc[oc].z + (double)acc[oc].w * acc[oc].w;
        wave_red2(s, qq);
        if (lane == 0) { srs[oc][wid] = s; srq[oc][wid] = qq; }
    }
    __syncthreads();
    if (tid < 10) {
        psum[tid * 49 + blockIdx.x] = srs[tid][0] + srs[tid][1] + srs[tid][2] + srs[tid][3];
        psum[490 + tid * 49 + blockIdx.x] = srq[tid][0] + srq[tid][1] + srq[tid][2] + srq[tid][3];
    }
}

// ---------------------------------------------------------------------------
// dw_small4_f: HIN->HOUT depthwise, 4-WAVE blocks: 640 blocks x 256 thr,
// wave w = pair (blockIdx*4+w) = (n,c). Fully wave-local (no barriers).
// psumIn [oc*NBIN+i] (+10*NBIN). psumOut [c*256+n] (+2560).
// ---------------------------------------------------------------------------
template<int HIN, int HOUT, int NBIN>
__global__ __launch_bounds__(256) void dw_small4_f(
    const float* __restrict__ in, const float* __restrict__ wts,
    const double* __restrict__ psumIn, double cnt,
    const float* __restrict__ g, const float* __restrict__ b,
    float* __restrict__ out, double* __restrict__ psum)
{
    constexpr int ISZ = HIN * HIN, OSZ = HOUT * HOUT;
    constexpr bool UP = (2 * (HOUT - 1) + 1) >= HIN;
    const int lane = threadIdx.x & 63, wid = threadIdx.x >> 6;
    const int pair = blockIdx.x * 4 + wid;   // [0, 2560)
    const int n = pair / 10, c = pair - n * 10;

    double s = 0.0, q = 0.0;
    for (int i = lane; i < NBIN; i += 64) {
        s += psumIn[c * NBIN + i];
        q += psumIn[10 * NBIN + c * NBIN + i];
    }
    wave_red2(s, q);
    s = __shfl(s, 0); q = __shfl(q, 0);
    const double mean = s / cnt;
    const double var = q / cnt - mean * mean;
    const double Ad = (1.0 / sqrt(var + 1e-5)) * (double)g[c];
    const float A = (float)Ad, B = (float)((double)b[c] - mean * Ad);

    float w9[9];
#pragma unroll
    for (int k = 0; k < 9; ++k) w9[k] = wts[c * 9 + k];
    const float* ip = in + (size_t)pair * ISZ;

    double ls = 0.0, lq = 0.0;
    if (lane < OSZ) {
        const int oh = lane / HOUT, ow = lane - oh * HOUT;
        float acc = 0.f;
#pragma unroll
        for (int kh = 0; kh < 3; ++kh) {
            const int ih = 2 * oh - 1 + kh;
            if (ih < 0) continue;
            if (UP && ih >= HIN) continue;
#pragma unroll
            for (int kw = 0; kw < 3; ++kw) {
                const int iw = 2 * ow - 1 + kw;
                if (iw < 0) continue;
                if (UP && iw >= HIN) continue;
                const float v = fmaxf(fmaf(ip[ih * HIN + iw], A, B), 0.f);
                acc = fmaf(v, w9[kh * 3 + kw], acc);
            }
        }
        out[(size_t)pair * OSZ + lane] = acc;
        ls = (double)acc; lq = (double)acc * (double)acc;
    }
    wave_red2(ls, lq);
    if (lane == 0) { psum[c * 256 + n] = ls; psum[2560 + c * 256 + n] = lq; }
}

// ---------------------------------------------------------------------------
// pw_sc_f: 1x1 10->10 over S px, scalar, FUSED 10-ch stats from psumIn
// [c*256+i] (+2560). grid = 256*S/256 blocks. psumOut [oc*G+blk].
// (unchanged from R10)
// ---------------------------------------------------------------------------
template<int S>
__global__ __launch_bounds__(256) void pw_sc_f(
    const float* __restrict__ in, const float* __restrict__ wts,
    const double* __restrict__ psumIn, double cnt,
    const float* __restrict__ g, const float* __restrict__ b,
    float* __restrict__ out, double* __restrict__ psum)
{
    __shared__ float sw[100], sA[10], sB[10];
    __shared__ double srs[10][4], srq[10][4];
    const int tid = threadIdx.x, lane = tid & 63, wid = tid >> 6;
    if (tid < 100) sw[tid] = wts[tid];
    for (int c = wid; c < 10; c += 4) {
        double s = 0.0, q = 0.0;
        for (int i = lane; i < 256; i += 64) {
            s += psumIn[c * 256 + i];
            q += psumIn[2560 + c * 256 + i];
        }
        wave_red2(s, q);
        if (lane == 0) {
            double mean = s / cnt;
            double var = q / cnt - mean * mean;
            double A = (1.0 / sqrt(var + 1e-5)) * (double)g[c];
            sA[c] = (float)A;
            sB[c] = (float)((double)b[c] - mean * A);
        }
    }
    __syncthreads();

    const int p = blockIdx.x * 256 + tid;
    const int n = p / S, px = p - n * S;
    const float* ip = in + (size_t)n * 10 * S + px;
    float v[10];
#pragma unroll
    for (int c = 0; c < 10; ++c)
        v[c] = fmaxf(fmaf(ip[c * S], sA[c], sB[c]), 0.f);
    float* op = out + (size_t)n * 10 * S + px;
    double ds[10], dq[10];
#pragma unroll
    for (int oc = 0; oc < 10; ++oc) {
        float a = 0.f;
#pragma unroll
        for (int c = 0; c < 10; ++c) a = fmaf(v[c], sw[oc * 10 + c], a);
        op[oc * S] = a;
        ds[oc] = (double)a; dq[oc] = (double)a * (double)a;
    }
#pragma unroll
    for (int oc = 0; oc < 10; ++oc) {
        double s = ds[oc], q = dq[oc];
        wave_red2(s, q);
        if (lane == 0) { srs[oc][wid] = s; srq[oc][wid] = q; }
    }
    __syncthreads();
    if (tid < 10) {
        const int G = gridDim.x;
        psum[tid * G + blockIdx.x] = srs[tid][0] + srs[tid][1] + srs[tid][2] + srs[tid][3];
        psum[10 * G + tid * G + blockIdx.x] = srq[tid][0] + srq[tid][1] + srq[tid][2] + srq[tid][3];
    }
}

// ---------------------------------------------------------------------------
// rollout_f: FUSED st7 finalize (psumIn [oc*16+i] (+160)) + feat + LSTM +
// JAX-exact threefry/Gumbel sampling. 256 blocks x 64 thr. (unchanged)
// ---------------------------------------------------------------------------
__global__ __launch_bounds__(64) void rollout_f(
    const float* __restrict__ t7, const double* __restrict__ psumIn,
    const float* __restrict__ g, const float* __restrict__ b,
    const float* __restrict__ wih0, const float* __restrict__ whh0,
    const float* __restrict__ bih0, const float* __restrict__ bhh0,
    const float* __restrict__ wih1, const float* __restrict__ whh1,
    const float* __restrict__ bih1, const float* __restrict__ bhh1,
    const float* __restrict__ head_w, const float* __restrict__ head_b,
    float* __restrict__ out)
{
    const int bb = blockIdx.x;
    const int l = threadIdx.x;
    __shared__ float gum[2][19][6];
    __shared__ float s_inp[12], s_h0[10], s_h1[10], s_gates[40], s_logits[12];

    // ---- RNG precompute ----
    {
        uint32_t k0 = 0u, k1 = 1u;
        const uint32_t m = (uint32_t)(l < 3 ? l : 0);
        for (int t = 0; t < 19; ++t) {
            uint32_t y0, y1;
            threefry2x32(k0, k1, 0u, m, y0, y1);
            const uint32_t nk0 = (uint32_t)__shfl((int)y0, 0);
            const uint32_t nk1 = (uint32_t)__shfl((int)y1, 0);
            const uint32_t ka0 = (uint32_t)__shfl((int)y0, 1);
            const uint32_t ka1 = (uint32_t)__shfl((int)y1, 1);
            const uint32_t kw0 = (uint32_t)__shfl((int)y0, 2);
            const uint32_t kw1 = (uint32_t)__shfl((int)y1, 2);
            if (l < 12) {
                const int path = l / 6;
                const int j = l - path * 6;
                const uint32_t kk0 = path ? kw0 : ka0;
                const uint32_t kk1 = path ? kw1 : ka1;
                const uint32_t flat = (uint32_t)(bb * 6 + j);
                uint32_t z0, z1;
                threefry2x32(kk0, kk1, 0u, flat, z0, z1);
                const uint32_t bits = z0 ^ z1;
                float u = __uint_as_float((bits >> 9) | 0x3f800000u) - 1.0f;
                if (u == 0.0f) u = 1.17549435e-38f;
                const double l1 = log((double)u);
                gum[path][t][j] = (float)(-log(-l1));
            }
            k0 = nk0; k1 = nk1;
        }
    }

    // ---- fused st7 finalize + feat ----
    if (l < 10) {
        double s = 0.0, q = 0.0;
#pragma unroll
        for (int i = 0; i < 16; ++i) {
            s += psumIn[l * 16 + i];
            q += psumIn[160 + l * 16 + i];
        }
        const double mean = s / 4096.0;
        const double var = q / 4096.0 - mean * mean;
        const double Ad = (1.0 / sqrt(var + 1e-5)) * (double)g[l];
        const float A = (float)Ad, B = (float)((double)b[l] - mean * Ad);
        const float* tp = t7 + (size_t)(bb * 10 + l) * 16;
        float f = 0.f;
#pragma unroll
        for (int i = 0; i < 16; ++i) f += fmaxf(fmaf(tp[i], A, B), 0.f);
        s_inp[l] = f * 0.0625f;
        s_h0[l] = 0.f; s_h1[l] = 0.f;
    }
    if (l >= 10 && l < 12) s_inp[l] = 0.f;

    // ---- weights into registers ----
    float wi0[12], wh0[10], bs0 = 0.f;
    float wi1[10], wh1[10], bs1 = 0.f;
    float hwr[10], hbr = 0.f;
    if (l < 40) {
#pragma unroll
        for (int k = 0; k < 12; ++k) wi0[k] = wih0[l * 12 + k];
#pragma unroll
        for (int k = 0; k < 10; ++k) wh0[k] = whh0[l * 10 + k];
        bs0 = bih0[l] + bhh0[l];
#pragma unroll
        for (int k = 0; k < 10; ++k) wi1[k] = wih1[l * 10 + k];
#pragma unroll
        for (int k = 0; k < 10; ++k) wh1[k] = whh1[l * 10 + k];
        bs1 = bih1[l] + bhh1[l];
    }
    if (l < 12) {
#pragma unroll
        for (int k = 0; k < 10; ++k) hwr[k] = head_w[l * 10 + k];
        hbr = head_b[l];
    }

    float c0 = 0.f, c1v = 0.f;
    __syncthreads();

    for (int t = 0; t < 19; ++t) {
        if (l < 40) {
            float gacc = bs0;
#pragma unroll
            for (int k = 0; k < 12; ++k) gacc = fmaf(s_inp[k], wi0[k], gacc);
#pragma unroll
            for (int k = 0; k < 10; ++k) gacc = fmaf(s_h0[k], wh0[k], gacc);
            s_gates[l] = gacc;
        }
        __syncthreads();
        if (l < 10) {
            const float gi = s_gates[l], gf = s_gates[10 + l], gg = s_gates[20 + l], go = s_gates[30 + l];
            c0 = sigf(gf) * c0 + sigf(gi) * tanhf(gg);
            s_h0[l] = sigf(go) * tanhf(c0);
        }
        __syncthreads();
        if (l < 40) {
            float gacc = bs1;
#pragma unroll
            for (int k = 0; k < 10; ++k) gacc = fmaf(s_h0[k], wi1[k], gacc);
#pragma unroll
            for (int k = 0; k < 10; ++k) gacc = fmaf(s_h1[k], wh1[k], gacc);
            s_gates[l] = gacc;
        }
        __syncthreads();
        if (l < 10) {
            const float gi = s_gates[l], gf = s_gates[10 + l], gg = s_gates[20 + l], go = s_gates[30 + l];
            c1v = sigf(gf) * c1v + sigf(gi) * tanhf(gg);
            s_h1[l] = sigf(go) * tanhf(c1v);
        }
        __syncthreads();
        if (l < 12) {
            float v = hbr;
#pragma unroll
            for (int k = 0; k < 10; ++k) v = fmaf(s_h1[k], hwr[k], v);
            s_logits[l] = v;
        }
        __syncthreads();
        if (l < 2) {
            const float* lg = &s_logits[l * 6];
            const float* gm = &gum[l][t][0];
            int best = 0; float bv = lg[0] + gm[0];
#pragma unroll
            for (int j = 1; j < 6; ++j) { const float v = lg[j] + gm[j]; if (v > bv) { bv = v; best = j; } }
            float mx = lg[0];
#pragma unroll
            for (int j = 1; j < 6; ++j) mx = fmaxf(mx, lg[j]);
            float se = 0.f;
#pragma unroll
            for (int j = 0; j < 6; ++j) se += expf(lg[j] - mx);
            const float lp = (lg[best] - mx) - logf(se);
            out[l * 4864 + bb * 19 + t] = (float)(best + 2);
            out[9728 + l * 4864 + bb * 19 + t] = lp;
            s_inp[10 + l] = (float)best;
        }
        __syncthreads();
    }
}

// ---------------------------------------------------------------------------
extern "C" void kernel_launch(void* const* d_in, const int* in_sizes, int n_in,
                              void* d_out, int out_size, void* d_ws, size_t ws_size,
                              hipStream_t stream)
{
    const float* x      = (const float*)d_in[0];
    const float* dw0_w  = (const float*)d_in[1];
    const float* bn0a_g = (const float*)d_in[2];
    const float* bn0a_b = (const float*)d_in[3];
    const float* pw0_w  = (const float*)d_in[4];
    const float* bn0b_g = (const float*)d_in[5];
    const float* bn0b_b = (const float*)d_in[6];
    const float* dwr_w  = (const float*)d_in[7];
    const float* bnra_g = (const float*)d_in[8];
    const float* bnra_b = (const float*)d_in[9];
    const float* pwr_w  = (const float*)d_in[10];
    const float* bnrb_g = (const float*)d_in[11];
    const float* bnrb_b = (const float*)d_in[12];
    const float* wih0   = (const float*)d_in[13];
    const float* whh0   = (const float*)d_in[14];
    const float* bih0   = (const float*)d_in[15];
    const float* bhh0   = (const float*)d_in[16];
    const float* wih1   = (const float*)d_in[17];
    const float* whh1   = (const float*)d_in[18];
    const float* bih1   = (const float*)d_in[19];
    const float* bhh1   = (const float*)d_in[20];
    const float* head_w = (const float*)d_in[21];
    const float* head_b = (const float*)d_in[22];
    float* out = (float*)d_out;

    char* ws = (char*)d_ws;
    size_t off = 0;
    auto take = [&](size_t bytes) -> char* {
        char* p = ws + off;
        off += (bytes + 255) & ~(size_t)255;
        return p;
    };
    float* y0     = (float*)take(12845056ull * 4);  // (256,64,28,28)
    float* t1     = (float*)take(2007040ull * 4);   // (256,10,28,28)
    float* t2     = (float*)take(501760ull * 4);    // (256,10,14,14)
    float* t3     = (float*)take(501760ull * 4);
    float* t4     = (float*)take(125440ull * 4);    // (256,10,7,7)
    float* t5     = (float*)take(125440ull * 4);
    float* t6     = (float*)take(40960ull * 4);     // (256,10,4,4)
    float* t7     = (float*)take(40960ull * 4);
    double* psumA = (double*)take(32768ull * 8);    // dw0: [c*256+n] (+16384)
    double* psumB = (double*)take(3920ull * 8);     // pw0: [oc*196+b] (+1960)
    double* psumC = (double*)take(5120ull * 8);     // dw1: [c*256+n] (+2560)
    double* psumD = (double*)take(980ull * 8);      // pw1: [oc*49+b] (+490)
    double* psumE = (double*)take(5120ull * 8);     // dw2: [c*256+n] (+2560)
    double* psumF = (double*)take(980ull * 8);      // pw2: [oc*49+b] (+490)
    double* psumG = (double*)take(5120ull * 8);     // dw3: [c*256+n] (+2560)
    double* psumH = (double*)take(320ull * 8);      // pw3: [oc*16+b] (+160)

    dw0_kernel<<<16384, 256, 0, stream>>>(x, dw0_w, y0, psumA);
    pw0_f<<<196, 256, 0, stream>>>(y0, pw0_w, psumA, bn0a_g, bn0a_b, t1, psumB);
    dw_mid_f<<<2560, 256, 0, stream>>>(t1, dwr_w, psumB, bn0b_g, bn0b_b, t2, psumC);
    pw_mid4_f<<<49, 256, 0, stream>>>(t2, pwr_w, psumC, 50176.0, bnra_g, bnra_b, t3, psumD);
    dw_small4_f<14, 7, 49><<<640, 256, 0, stream>>>(t3, dwr_w + 90, psumD, 50176.0,
                                                    bnrb_g, bnrb_b, t4, psumE);
    pw_sc_f<49><<<49, 256, 0, stream>>>(t4, pwr_w + 100, psumE, 12544.0,
                                        bnra_g + 10, bnra_b + 10, t5, psumF);
    dw_small4_f<7, 4, 49><<<640, 256, 0, stream>>>(t5, dwr_w + 180, psumF, 12544.0,
                                                   bnrb_g + 10, bnrb_b + 10, t6, psumG);
    pw_sc_f<16><<<16, 256, 0, stream>>>(t6, pwr_w + 200, psumG, 4096.0,
                                        bnra_g + 20, bnra_b + 20, t7, psumH);
    rollout_f<<<256, 64, 0, stream>>>(t7, psumH, bnrb_g + 20, bnrb_b + 20,
                                      wih0, whh0, bih0, bhh0, wih1, whh1, bih1, bhh1,
                                      head_w, head_b, out);
}

// Round 12
// 161.222 us; speedup vs baseline: 1.0640x; 1.0640x over previous
//
#include <hip/hip_runtime.h>
#include <stdint.h>
#include <math.h>

// ---------------------------------------------------------------------------
// Threefry-2x32 (JAX-compatible, 20 rounds)
// ---------------------------------------------------------------------------
#define TF_ROUND(r) do { x0 += x1; x1 = (x1 << (r)) | (x1 >> (32 - (r))); x1 ^= x0; } while (0)

__device__ __forceinline__ void threefry2x32(uint32_t k0, uint32_t k1,
                                             uint32_t x0, uint32_t x1,
                                             uint32_t& y0, uint32_t& y1)
{
    uint32_t k2 = k0 ^ k1 ^ 0x1BD11BDAu;
    x0 += k0; x1 += k1;
    TF_ROUND(13); TF_ROUND(15); TF_ROUND(26); TF_ROUND(6);
    x0 += k1; x1 += k2 + 1u;
    TF_ROUND(17); TF_ROUND(29); TF_ROUND(16); TF_ROUND(24);
    x0 += k2; x1 += k0 + 2u;
    TF_ROUND(13); TF_ROUND(15); TF_ROUND(26); TF_ROUND(6);
    x0 += k0; x1 += k1 + 3u;
    TF_ROUND(17); TF_ROUND(29); TF_ROUND(16); TF_ROUND(24);
    x0 += k1; x1 += k2 + 4u;
    TF_ROUND(13); TF_ROUND(15); TF_ROUND(26); TF_ROUND(6);
    y0 = x0 + k2; y1 = x1 + k0 + 5u;
}

__device__ __forceinline__ void wave_red2(double& s, double& q) {
    for (int off = 32; off > 0; off >>= 1) {
        s += __shfl_down(s, off);
        q += __shfl_down(q, off);
    }
}

__device__ __forceinline__ float sigf(float x) { return 0.5f + 0.5f * tanhf(0.5f * x); }

// ---------------------------------------------------------------------------
// dw0: depthwise 3x3 s2 p1, 56->28 (~47us measured). One block per (n,c)
// plane; float4 LDS staging; quad-per-thread register-cached conv;
// single-barrier shuffle f64 stats. psum: sum [c*256+n], sumsq [16384+...].
// ---------------------------------------------------------------------------
__global__ __launch_bounds__(256) void dw0_kernel(
    const float* __restrict__ in, const float* __restrict__ wts,
    float* __restrict__ out, double* __restrict__ psum)
{
    __shared__ float tile[3136];
    __shared__ double sred[8];
    const int tid = threadIdx.x, lane = tid & 63, wid = tid >> 6;
    const int blk = blockIdx.x;
    const int n = blk >> 6, c = blk & 63;

    const float4* ip4 = (const float4*)(in + (size_t)blk * 3136);
    float4* tp4 = (float4*)tile;
#pragma unroll
    for (int r = 0; r < 3; ++r) tp4[tid + r * 256] = ip4[tid + r * 256];
    if (tid < 16) tp4[768 + tid] = ip4[768 + tid];
    float w9[9];
#pragma unroll
    for (int k = 0; k < 9; ++k) w9[k] = wts[c * 9 + k];
    __syncthreads();

    double ls = 0.0, lq = 0.0;
    if (tid < 196) {
        const int oh = tid / 7, ow0 = (tid - oh * 7) * 4;
        const int col0 = 2 * ow0 - 1;
        float rv[3][9];
#pragma unroll
        for (int kh = 0; kh < 3; ++kh) {
            const int ih = 2 * oh - 1 + kh;           // max 55 < 56
            if (ih >= 0) {
                const float* rp = tile + ih * 56 + col0;
                rv[kh][0] = (col0 >= 0) ? rp[0] : 0.f;
#pragma unroll
                for (int j = 1; j < 9; ++j) rv[kh][j] = rp[j];
            } else {
#pragma unroll
                for (int j = 0; j < 9; ++j) rv[kh][j] = 0.f;
            }
        }
        float a0 = 0.f, a1 = 0.f, a2 = 0.f, a3 = 0.f;
#pragma unroll
        for (int kh = 0; kh < 3; ++kh)
#pragma unroll
            for (int kw = 0; kw < 3; ++kw) {
                const float w = w9[kh * 3 + kw];
                a0 = fmaf(rv[kh][0 + kw], w, a0);
                a1 = fmaf(rv[kh][2 + kw], w, a1);
                a2 = fmaf(rv[kh][4 + kw], w, a2);
                a3 = fmaf(rv[kh][6 + kw], w, a3);
            }
        *(float4*)(out + (size_t)blk * 784 + oh * 28 + ow0) = make_float4(a0, a1, a2, a3);
        ls = (double)a0 + (double)a1 + (double)a2 + (double)a3;
        lq = (double)a0 * a0 + (double)a1 * a1 + (double)a2 * a2 + (double)a3 * a3;
    }
    wave_red2(ls, lq);
    if (lane == 0) { sred[wid] = ls; sred[4 + wid] = lq; }
    __syncthreads();
    if (tid == 0) {
        psum[c * 256 + n] = sred[0] + sred[1] + sred[2] + sred[3];
        psum[16384 + c * 256 + n] = sred[4] + sred[5] + sred[6] + sred[7];
    }
}

// ---------------------------------------------------------------------------
// red_chan: per-channel finalize psum[c*NB+i] (+C*NB sumsq) -> st[c]=(A,B).
// ---------------------------------------------------------------------------
__global__ __launch_bounds__(256) void red_chan(
    const double* __restrict__ psum, int NB, double count,
    const float* __restrict__ g, const float* __restrict__ b,
    float2* __restrict__ stats, int C)
{
    __shared__ double sred[8];
    const int c = blockIdx.x, tid = threadIdx.x, lane = tid & 63, wid = tid >> 6;
    double s = 0.0, q = 0.0;
    for (int i = tid; i < NB; i += 256) {
        s += psum[(size_t)c * NB + i];
        q += psum[(size_t)C * NB + (size_t)c * NB + i];
    }
    wave_red2(s, q);
    if (lane == 0) { sred[wid] = s; sred[4 + wid] = q; }
    __syncthreads();
    if (tid == 0) {
        double ss = sred[0] + sred[1] + sred[2] + sred[3];
        double qq = sred[4] + sred[5] + sred[6] + sred[7];
        double mean = ss / count;
        double var = qq / count - mean * mean;
        double A = (1.0 / sqrt(var + 1e-5)) * (double)g[c];
        stats[c] = make_float2((float)A, (float)((double)b[c] - mean * A));
    }
}

// ---------------------------------------------------------------------------
// pw0: 1x1 conv 64->10 with BN+ReLU of input (st0 float2), float4 pixels.
// 196 blocks x 256 thr = 50176 quads. psum out [oc*196+blk] (+1960).
// ---------------------------------------------------------------------------
__global__ __launch_bounds__(256) void pw0_kernel(
    const float* __restrict__ in, const float* __restrict__ wts,
    const float2* __restrict__ st0, float* __restrict__ out,
    double* __restrict__ psum)
{
    __shared__ float sw[640];
    __shared__ float2 sst[64];
    __shared__ double srs[10][4], srq[10][4];
    const int tid = threadIdx.x, lane = tid & 63, wid = tid >> 6;
    for (int i = tid; i < 640; i += 256) sw[i] = wts[i];
    if (tid < 64) sst[tid] = st0[tid];
    __syncthreads();

    const int p = blockIdx.x * 256 + tid;       // [0, 50176) quads
    const int n = p / 196, sp4 = p - n * 196;
    const float4* ip4 = (const float4*)in + (size_t)n * 12544 + sp4;
    float4 acc[10];
#pragma unroll
    for (int oc = 0; oc < 10; ++oc) acc[oc] = make_float4(0.f, 0.f, 0.f, 0.f);
#pragma unroll 8
    for (int c = 0; c < 64; ++c) {
        float4 v = ip4[c * 196];
        const float2 stc = sst[c];
        v.x = fmaxf(fmaf(v.x, stc.x, stc.y), 0.f);
        v.y = fmaxf(fmaf(v.y, stc.x, stc.y), 0.f);
        v.z = fmaxf(fmaf(v.z, stc.x, stc.y), 0.f);
        v.w = fmaxf(fmaf(v.w, stc.x, stc.y), 0.f);
#pragma unroll
        for (int oc = 0; oc < 10; ++oc) {
            const float wv = sw[oc * 64 + c];
            acc[oc].x = fmaf(v.x, wv, acc[oc].x);
            acc[oc].y = fmaf(v.y, wv, acc[oc].y);
            acc[oc].z = fmaf(v.z, wv, acc[oc].z);
            acc[oc].w = fmaf(v.w, wv, acc[oc].w);
        }
    }
#pragma unroll
    for (int oc = 0; oc < 10; ++oc)
        ((float4*)out)[(size_t)(n * 10 + oc) * 196 + sp4] = acc[oc];

#pragma unroll
    for (int oc = 0; oc < 10; ++oc) {
        double s = (double)acc[oc].x + (double)acc[oc].y + (double)acc[oc].z + (double)acc[oc].w;
        double q = (double)acc[oc].x * acc[oc].x + (double)acc[oc].y * acc[oc].y
                 + (double)acc[oc].z * acc[oc].z + (double)acc[oc].w * acc[oc].w;
        wave_red2(s, q);
        if (lane == 0) { srs[oc][wid] = s; srq[oc][wid] = q; }
    }
    __syncthreads();
    if (tid < 10) {
        psum[tid * 196 + blockIdx.x] = srs[tid][0] + srs[tid][1] + srs[tid][2] + srs[tid][3];
        psum[1960 + tid * 196 + blockIdx.x] = srq[tid][0] + srq[tid][1] + srq[tid][2] + srq[tid][3];
    }
}

// ---------------------------------------------------------------------------
// dw_mid: 28->14 depthwise. 2560 blocks = (n*10+c), 256 thr. LDS-stage the
// 784-float plane with BN+ReLU (st float2), conv, psum [c*256+n] (+2560).
// ---------------------------------------------------------------------------
__global__ __launch_bounds__(256) void dw_mid(
    const float* __restrict__ in, const float* __restrict__ wts,
    const float2* __restrict__ stIn, float* __restrict__ out,
    double* __restrict__ psum)
{
    __shared__ float tile[784];
    __shared__ double sred[8];
    const int tid = threadIdx.x, lane = tid & 63, wid = tid >> 6;
    const int blk = blockIdx.x;
    const int n = blk / 10, c = blk - n * 10;
    const float2 stc = stIn[c];
    float w9[9];
#pragma unroll
    for (int k = 0; k < 9; ++k) w9[k] = wts[c * 9 + k];

    const float4* ip4 = (const float4*)(in + (size_t)blk * 784);
    if (tid < 196) {
        float4 v = ip4[tid];
        v.x = fmaxf(fmaf(v.x, stc.x, stc.y), 0.f);
        v.y = fmaxf(fmaf(v.y, stc.x, stc.y), 0.f);
        v.z = fmaxf(fmaf(v.z, stc.x, stc.y), 0.f);
        v.w = fmaxf(fmaf(v.w, stc.x, stc.y), 0.f);
        ((float4*)tile)[tid] = v;
    }
    __syncthreads();

    double ls = 0.0, lq = 0.0;
    if (tid < 196) {
        const int oh = tid / 14, ow = tid - oh * 14;
        float acc = 0.f;
#pragma unroll
        for (int kh = 0; kh < 3; ++kh) {
            const int ih = 2 * oh - 1 + kh;           // max 27 < 28
            if (ih < 0) continue;
#pragma unroll
            for (int kw = 0; kw < 3; ++kw) {
                const int iw = 2 * ow - 1 + kw;
                if (iw < 0) continue;
                acc = fmaf(tile[ih * 28 + iw], w9[kh * 3 + kw], acc);
            }
        }
        out[(size_t)blk * 196 + tid] = acc;
        ls = (double)acc; lq = (double)acc * (double)acc;
    }
    wave_red2(ls, lq);
    if (lane == 0) { sred[wid] = ls; sred[4 + wid] = lq; }
    __syncthreads();
    if (tid == 0) {
        psum[c * 256 + n] = sred[0] + sred[1] + sred[2] + sred[3];
        psum[2560 + c * 256 + n] = sred[4] + sred[5] + sred[6] + sred[7];
    }
}

// ---------------------------------------------------------------------------
// pw_mid4: 1x1 conv 10->10 over 196-px planes, float4 quads. 49 blocks x 256
// thr = 12544 (n,quad) pairs. psum [oc*49+blk] (+490).
// ---------------------------------------------------------------------------
__global__ __launch_bounds__(256) void pw_mid4(
    const float* __restrict__ in, const float* __restrict__ wts,
    const float2* __restrict__ stIn, float* __restrict__ out,
    double* __restrict__ psum)
{
    __shared__ float sw[100];
    __shared__ float2 sst[10];
    __shared__ double srs[10][4], srq[10][4];
    const int tid = threadIdx.x, lane = tid & 63, wid = tid >> 6;
    if (tid < 100) sw[tid] = wts[tid];
    if (tid < 10) sst[tid] = stIn[tid];
    __syncthreads();

    const int p = blockIdx.x * 256 + tid;       // [0, 12544) quads
    const int n = p / 49, q = p - n * 49;
    const float4* ip4 = (const float4*)in + (size_t)n * 490 + q;
    float4 acc[10];
#pragma unroll
    for (int oc = 0; oc < 10; ++oc) acc[oc] = make_float4(0.f, 0.f, 0.f, 0.f);
#pragma unroll
    for (int c = 0; c < 10; ++c) {
        float4 v = ip4[c * 49];
        const float2 stc = sst[c];
        v.x = fmaxf(fmaf(v.x, stc.x, stc.y), 0.f);
        v.y = fmaxf(fmaf(v.y, stc.x, stc.y), 0.f);
        v.z = fmaxf(fmaf(v.z, stc.x, stc.y), 0.f);
        v.w = fmaxf(fmaf(v.w, stc.x, stc.y), 0.f);
#pragma unroll
        for (int oc = 0; oc < 10; ++oc) {
            const float wv = sw[oc * 10 + c];
            acc[oc].x = fmaf(v.x, wv, acc[oc].x);
            acc[oc].y = fmaf(v.y, wv, acc[oc].y);
            acc[oc].z = fmaf(v.z, wv, acc[oc].z);
            acc[oc].w = fmaf(v.w, wv, acc[oc].w);
        }
    }
#pragma unroll
    for (int oc = 0; oc < 10; ++oc)
        ((float4*)out)[(size_t)n * 490 + oc * 49 + q] = acc[oc];

#pragma unroll
    for (int oc = 0; oc < 10; ++oc) {
        double s = (double)acc[oc].x + (double)acc[oc].y + (double)acc[oc].z + (double)acc[oc].w;
        double qq = (double)acc[oc].x * acc[oc].x + (double)acc[oc].y * acc[oc].y
                  + (double)acc[oc].z * acc[oc].z + (double)acc[oc].w * acc[oc].w;
        wave_red2(s, qq);
        if (lane == 0) { srs[oc][wid] = s; srq[oc][wid] = qq; }
    }
    __syncthreads();
    if (tid < 10) {
        psum[tid * 49 + blockIdx.x] = srs[tid][0] + srs[tid][1] + srs[tid][2] + srs[tid][3];
        psum[490 + tid * 49 + blockIdx.x] = srq[tid][0] + srq[tid][1] + srq[tid][2] + srq[tid][3];
    }
}

// ---------------------------------------------------------------------------
// dw_small: HIN->HOUT depthwise, 2560 blocks = (n*10+c), 64 thr, direct
// global reads (plane L2-resident), psum [c*256+n] (+2560).
// ---------------------------------------------------------------------------
template<int HIN, int HOUT>
__global__ __launch_bounds__(64) void dw_small(
    const float* __restrict__ in, const float* __restrict__ wts,
    const float2* __restrict__ stIn, float* __restrict__ out,
    double* __restrict__ psum)
{
    constexpr int ISZ = HIN * HIN, OSZ = HOUT * HOUT;
    constexpr bool UP = (2 * (HOUT - 1) + 1) >= HIN;
    const int lane = threadIdx.x;
    const int blk = blockIdx.x;
    const int n = blk / 10, c = blk - n * 10;
    const float2 stc = stIn[c];
    float w9[9];
#pragma unroll
    for (int k = 0; k < 9; ++k) w9[k] = wts[c * 9 + k];
    const float* ip = in + (size_t)blk * ISZ;

    double s = 0.0, q = 0.0;
    if (lane < OSZ) {
        const int oh = lane / HOUT, ow = lane - oh * HOUT;
        float acc = 0.f;
#pragma unroll
        for (int kh = 0; kh < 3; ++kh) {
            const int ih = 2 * oh - 1 + kh;
            if (ih < 0) continue;
            if (UP && ih >= HIN) continue;
#pragma unroll
            for (int kw = 0; kw < 3; ++kw) {
                const int iw = 2 * ow - 1 + kw;
                if (iw < 0) continue;
                if (UP && iw >= HIN) continue;
                const float v = fmaxf(fmaf(ip[ih * HIN + iw], stc.x, stc.y), 0.f);
                acc = fmaf(v, w9[kh * 3 + kw], acc);
            }
        }
        out[(size_t)blk * OSZ + lane] = acc;
        s = (double)acc; q = (double)acc * (double)acc;
    }
    wave_red2(s, q);
    if (lane == 0) { psum[c * 256 + n] = s; psum[2560 + c * 256 + n] = q; }
}

// ---------------------------------------------------------------------------
// pw_sc: 1x1 conv 10->10 over S px, scalar, grid = 256*S/256 blocks.
// psum [oc*G+blk] (+10*G).
// ---------------------------------------------------------------------------
template<int S>
__global__ __launch_bounds__(256) void pw_sc(
    const float* __restrict__ in, const float* __restrict__ wts,
    const float2* __restrict__ stIn, float* __restrict__ out,
    double* __restrict__ psum)
{
    __shared__ float sw[100];
    __shared__ float2 sst[10];
    __shared__ double srs[10][4], srq[10][4];
    const int tid = threadIdx.x, lane = tid & 63, wid = tid >> 6;
    if (tid < 100) sw[tid] = wts[tid];
    if (tid < 10) sst[tid] = stIn[tid];
    __syncthreads();

    const int p = blockIdx.x * 256 + tid;
    const int n = p / S, px = p - n * S;
    const float* ip = in + (size_t)n * 10 * S + px;
    float v[10];
#pragma unroll
    for (int c = 0; c < 10; ++c)
        v[c] = fmaxf(fmaf(ip[c * S], sst[c].x, sst[c].y), 0.f);
    float* op = out + (size_t)n * 10 * S + px;
    double ds[10], dq[10];
#pragma unroll
    for (int oc = 0; oc < 10; ++oc) {
        float a = 0.f;
#pragma unroll
        for (int c = 0; c < 10; ++c) a = fmaf(v[c], sw[oc * 10 + c], a);
        op[oc * S] = a;
        ds[oc] = (double)a; dq[oc] = (double)a * (double)a;
    }
#pragma unroll
    for (int oc = 0; oc < 10; ++oc) {
        double s = ds[oc], q = dq[oc];
        wave_red2(s, q);
        if (lane == 0) { srs[oc][wid] = s; srq[oc][wid] = q; }
    }
    __syncthreads();
    if (tid < 10) {
        const int G = gridDim.x;
        psum[tid * G + blockIdx.x] = srs[tid][0] + srs[tid][1] + srs[tid][2] + srs[tid][3];
        psum[10 * G + tid * G + blockIdx.x] = srq[tid][0] + srq[tid][1] + srq[tid][2] + srq[tid][3];
    }
}

// ---------------------------------------------------------------------------
// LSTM rollout + JAX-exact threefry/Gumbel sampling; reads st7 directly.
// ---------------------------------------------------------------------------
__global__ __launch_bounds__(64) void rollout_kernel(
    const float* __restrict__ t7, const float2* __restrict__ st7,
    const float* __restrict__ wih0, const float* __restrict__ whh0,
    const float* __restrict__ bih0, const float* __restrict__ bhh0,
    const float* __restrict__ wih1, const float* __restrict__ whh1,
    const float* __restrict__ bih1, const float* __restrict__ bhh1,
    const float* __restrict__ head_w, const float* __restrict__ head_b,
    float* __restrict__ out)
{
    const int bb = blockIdx.x;
    const int l = threadIdx.x;
    __shared__ float gum[2][19][6];
    __shared__ float s_inp[12], s_h0[10], s_h1[10], s_gates[40], s_logits[12];

    // ---- RNG precompute ----
    {
        uint32_t k0 = 0u, k1 = 1u;
        const uint32_t m = (uint32_t)(l < 3 ? l : 0);
        for (int t = 0; t < 19; ++t) {
            uint32_t y0, y1;
            threefry2x32(k0, k1, 0u, m, y0, y1);
            const uint32_t nk0 = (uint32_t)__shfl((int)y0, 0);
            const uint32_t nk1 = (uint32_t)__shfl((int)y1, 0);
            const uint32_t ka0 = (uint32_t)__shfl((int)y0, 1);
            const uint32_t ka1 = (uint32_t)__shfl((int)y1, 1);
            const uint32_t kw0 = (uint32_t)__shfl((int)y0, 2);
            const uint32_t kw1 = (uint32_t)__shfl((int)y1, 2);
            if (l < 12) {
                const int path = l / 6;
                const int j = l - path * 6;
                const uint32_t kk0 = path ? kw0 : ka0;
                const uint32_t kk1 = path ? kw1 : ka1;
                const uint32_t flat = (uint32_t)(bb * 6 + j);
                uint32_t z0, z1;
                threefry2x32(kk0, kk1, 0u, flat, z0, z1);
                const uint32_t bits = z0 ^ z1;
                float u = __uint_as_float((bits >> 9) | 0x3f800000u) - 1.0f;
                if (u == 0.0f) u = 1.17549435e-38f;
                const double l1 = log((double)u);
                gum[path][t][j] = (float)(-log(-l1));
            }
            k0 = nk0; k1 = nk1;
        }
    }

    // ---- feat from t7 + st7 ----
    if (l < 10) {
        const float2 stc = st7[l];
        const float* tp = t7 + (size_t)(bb * 10 + l) * 16;
        float f = 0.f;
#pragma unroll
        for (int i = 0; i < 16; ++i) f += fmaxf(fmaf(tp[i], stc.x, stc.y), 0.f);
        s_inp[l] = f * 0.0625f;
        s_h0[l] = 0.f; s_h1[l] = 0.f;
    }
    if (l >= 10 && l < 12) s_inp[l] = 0.f;

    // ---- weights into registers ----
    float wi0[12], wh0[10], bs0 = 0.f;
    float wi1[10], wh1[10], bs1 = 0.f;
    float hwr[10], hbr = 0.f;
    if (l < 40) {
#pragma unroll
        for (int k = 0; k < 12; ++k) wi0[k] = wih0[l * 12 + k];
#pragma unroll
        for (int k = 0; k < 10; ++k) wh0[k] = whh0[l * 10 + k];
        bs0 = bih0[l] + bhh0[l];
#pragma unroll
        for (int k = 0; k < 10; ++k) wi1[k] = wih1[l * 10 + k];
#pragma unroll
        for (int k = 0; k < 10; ++k) wh1[k] = whh1[l * 10 + k];
        bs1 = bih1[l] + bhh1[l];
    }
    if (l < 12) {
#pragma unroll
        for (int k = 0; k < 10; ++k) hwr[k] = head_w[l * 10 + k];
        hbr = head_b[l];
    }

    float c0 = 0.f, c1v = 0.f;
    __syncthreads();

    for (int t = 0; t < 19; ++t) {
        if (l < 40) {
            float gacc = bs0;
#pragma unroll
            for (int k = 0; k < 12; ++k) gacc = fmaf(s_inp[k], wi0[k], gacc);
#pragma unroll
            for (int k = 0; k < 10; ++k) gacc = fmaf(s_h0[k], wh0[k], gacc);
            s_gates[l] = gacc;
        }
        __syncthreads();
        if (l < 10) {
            const float gi = s_gates[l], gf = s_gates[10 + l], gg = s_gates[20 + l], go = s_gates[30 + l];
            c0 = sigf(gf) * c0 + sigf(gi) * tanhf(gg);
            s_h0[l] = sigf(go) * tanhf(c0);
        }
        __syncthreads();
        if (l < 40) {
            float gacc = bs1;
#pragma unroll
            for (int k = 0; k < 10; ++k) gacc = fmaf(s_h0[k], wi1[k], gacc);
#pragma unroll
            for (int k = 0; k < 10; ++k) gacc = fmaf(s_h1[k], wh1[k], gacc);
            s_gates[l] = gacc;
        }
        __syncthreads();
        if (l < 10) {
            const float gi = s_gates[l], gf = s_gates[10 + l], gg = s_gates[20 + l], go = s_gates[30 + l];
            c1v = sigf(gf) * c1v + sigf(gi) * tanhf(gg);
            s_h1[l] = sigf(go) * tanhf(c1v);
        }
        __syncthreads();
        if (l < 12) {
            float v = hbr;
#pragma unroll
            for (int k = 0; k < 10; ++k) v = fmaf(s_h1[k], hwr[k], v);
            s_logits[l] = v;
        }
        __syncthreads();
        if (l < 2) {
            const float* lg = &s_logits[l * 6];
            const float* gm = &gum[l][t][0];
            int best = 0; float bv = lg[0] + gm[0];
#pragma unroll
            for (int j = 1; j < 6; ++j) { const float v = lg[j] + gm[j]; if (v > bv) { bv = v; best = j; } }
            float mx = lg[0];
#pragma unroll
            for (int j = 1; j < 6; ++j) mx = fmaxf(mx, lg[j]);
            float se = 0.f;
#pragma unroll
            for (int j = 0; j < 6; ++j) se += expf(lg[j] - mx);
            const float lp = (lg[best] - mx) - logf(se);
            out[l * 4864 + bb * 19 + t] = (float)(best + 2);
            out[9728 + l * 4864 + bb * 19 + t] = lp;
            s_inp[10 + l] = (float)best;
        }
        __syncthreads();
    }
}

// ---------------------------------------------------------------------------
extern "C" void kernel_launch(void* const* d_in, const int* in_sizes, int n_in,
                              void* d_out, int out_size, void* d_ws, size_t ws_size,
                              hipStream_t stream)
{
    const float* x      = (const float*)d_in[0];
    const float* dw0_w  = (const float*)d_in[1];
    const float* bn0a_g = (const float*)d_in[2];
    const float* bn0a_b = (const float*)d_in[3];
    const float* pw0_w  = (const float*)d_in[4];
    const float* bn0b_g = (const float*)d_in[5];
    const float* bn0b_b = (const float*)d_in[6];
    const float* dwr_w  = (const float*)d_in[7];
    const float* bnra_g = (const float*)d_in[8];
    const float* bnra_b = (const float*)d_in[9];
    const float* pwr_w  = (const float*)d_in[10];
    const float* bnrb_g = (const float*)d_in[11];
    const float* bnrb_b = (const float*)d_in[12];
    const float* wih0   = (const float*)d_in[13];
    const float* whh0   = (const float*)d_in[14];
    const float* bih0   = (const float*)d_in[15];
    const float* bhh0   = (const float*)d_in[16];
    const float* wih1   = (const float*)d_in[17];
    const float* whh1   = (const float*)d_in[18];
    const float* bih1   = (const float*)d_in[19];
    const float* bhh1   = (const float*)d_in[20];
    const float* head_w = (const float*)d_in[21];
    const float* head_b = (const float*)d_in[22];
    float* out = (float*)d_out;

    char* ws = (char*)d_ws;
    size_t off = 0;
    auto take = [&](size_t bytes) -> char* {
        char* p = ws + off;
        off += (bytes + 255) & ~(size_t)255;
        return p;
    };
    float* y0     = (float*)take(12845056ull * 4);  // (256,64,28,28)
    float* t1     = (float*)take(2007040ull * 4);   // (256,10,28,28)
    float* t2     = (float*)take(501760ull * 4);    // (256,10,14,14)
    float* t3     = (float*)take(501760ull * 4);
    float* t4     = (float*)take(125440ull * 4);    // (256,10,7,7)
    float* t5     = (float*)take(125440ull * 4);
    float* t6     = (float*)take(40960ull * 4);     // (256,10,4,4)
    float* t7     = (float*)take(40960ull * 4);
    double* psumA = (double*)take(32768ull * 8);    // dw0: [c*256+n] (+16384)
    double* psumB = (double*)take(3920ull * 8);     // pw0: [oc*196+b] (+1960)
    double* psumC = (double*)take(5120ull * 8);     // dw1: [c*256+n] (+2560)
    double* psumD = (double*)take(980ull * 8);      // pw1: [oc*49+b] (+490)
    double* psumE = (double*)take(5120ull * 8);     // dw2
    double* psumF = (double*)take(980ull * 8);      // pw2: [oc*49+b] (+490)
    double* psumG = (double*)take(5120ull * 8);     // dw3
    double* psumH = (double*)take(320ull * 8);      // pw3: [oc*16+b] (+160)
    float2* st0   = (float2*)take(64 * sizeof(float2));
    float2* st1   = (float2*)take(16 * sizeof(float2));
    float2* st2   = (float2*)take(16 * sizeof(float2));
    float2* st3   = (float2*)take(16 * sizeof(float2));
    float2* st4   = (float2*)take(16 * sizeof(float2));
    float2* st5   = (float2*)take(16 * sizeof(float2));
    float2* st6   = (float2*)take(16 * sizeof(float2));
    float2* st7   = (float2*)take(16 * sizeof(float2));

    dw0_kernel<<<16384, 256, 0, stream>>>(x, dw0_w, y0, psumA);
    red_chan<<<64, 256, 0, stream>>>(psumA, 256, 200704.0, bn0a_g, bn0a_b, st0, 64);
    pw0_kernel<<<196, 256, 0, stream>>>(y0, pw0_w, st0, t1, psumB);
    red_chan<<<10, 256, 0, stream>>>(psumB, 196, 200704.0, bn0b_g, bn0b_b, st1, 10);
    dw_mid<<<2560, 256, 0, stream>>>(t1, dwr_w, st1, t2, psumC);
    red_chan<<<10, 256, 0, stream>>>(psumC, 256, 50176.0, bnra_g, bnra_b, st2, 10);
    pw_mid4<<<49, 256, 0, stream>>>(t2, pwr_w, st2, t3, psumD);
    red_chan<<<10, 256, 0, stream>>>(psumD, 49, 50176.0, bnrb_g, bnrb_b, st3, 10);
    dw_small<14, 7><<<2560, 64, 0, stream>>>(t3, dwr_w + 90, st3, t4, psumE);
    red_chan<<<10, 256, 0, stream>>>(psumE, 256, 12544.0, bnra_g + 10, bnra_b + 10, st4, 10);
    pw_sc<49><<<49, 256, 0, stream>>>(t4, pwr_w + 100, st4, t5, psumF);
    red_chan<<<10, 256, 0, stream>>>(psumF, 49, 12544.0, bnrb_g + 10, bnrb_b + 10, st5, 10);
    dw_small<7, 4><<<2560, 64, 0, stream>>>(t5, dwr_w + 180, st5, t6, psumG);
    red_chan<<<10, 256, 0, stream>>>(psumG, 256, 4096.0, bnra_g + 20, bnra_b + 20, st6, 10);
    pw_sc<16><<<16, 256, 0, stream>>>(t6, pwr_w + 200, st6, t7, psumH);
    red_chan<<<10, 256, 0, stream>>>(psumH, 16, 4096.0, bnrb_g + 20, bnrb_b + 20, st7, 10);
    rollout_kernel<<<256, 64, 0, stream>>>(t7, st7, wih0, whh0, bih0, bhh0,
                                           wih1, whh1, bih1, bhh1, head_w, head_b, out);
}